// Round 5
// baseline (5788.129 us; speedup 1.0000x reference)
//
#include <hip/hip_runtime.h>
#include <cmath>

#define NB 256            // 16 batch groups x 16 unit blocks -> 1 block/CU
#define NT 512
#define NG 16             // batch groups
#define GB 16             // blocks per group
#define B_ 256
#define T_ 256
#define I_ 64
#define H_ 512
#define G4H 2048
#define BT 16             // batch rows per block
#define UT 32             // hidden units per block -> 128 z cols, 8 waves = 8 N-tiles
#define ZP 132            // zs row stride (128 + 4)
#define NFC 18            // K chunks of 32
#define CPQ 17            // cells (16B) per q-group: 16 rows + 1 pad
#define CSTR 68           // cell stride per chunk (4*17)
#define NCELL 1224        // 18*68
#define POLL_N 64         // sc0-poll attempts before device-scope fallback
#define R_ON_F 0.05f
#define ALPHA_F 1.0e-3f
#define LN_EPS_F 1.0e-5f

typedef _Float16 h8 __attribute__((ext_vector_type(8)));
typedef _Float16 h4v __attribute__((ext_vector_type(4)));
typedef float f4 __attribute__((ext_vector_type(4)));
typedef float v4f __attribute__((ext_vector_type(4)));
typedef unsigned u4 __attribute__((ext_vector_type(4)));
typedef unsigned short us4 __attribute__((ext_vector_type(4)));

// Packed hidden-state double buffer: fp16(h)<<16 | (launch_tag<<8 | t+1).
// Launch-tagged epochs: stale lines from prior launches/replays never
// equality-match, so NO zeroing and NO startup barrier are needed.
// Writers pair-store (sc0 sc1 -> IF$ device-visible, then sc0 -> local L2,
// same value). Readers poll sc0 (fast L2 hit when the group is co-located
// on one XCD -- the expected round-robin case) and fall back to sc0 sc1
// after POLL_N misses (correct under ANY placement; degrades, never hangs).
__device__ __align__(16) unsigned g_hp[2][B_ * H_];
// Exact fp32 final h for the LN/dense epilogue (written only at t = T_-1);
// only ever accessed device-scope (sc0 sc1) on both sides.
__device__ __align__(16) float g_hf[B_ * H_];

struct alignas(256) PadCnt { unsigned v; unsigned pad[63]; };
__device__ PadCnt g_flag[NG][GB];   // FINAL handoff only; tagged values
__device__ unsigned g_launch_cnt;   // never reset; tag = (cnt/NB)+1

__device__ __forceinline__ float fast_sigmoid(float x) {
    return __builtin_amdgcn_rcpf(1.f + __expf(-x));
}
__device__ __forceinline__ float fast_tanh(float x) {
    return 1.f - 2.f * __builtin_amdgcn_rcpf(__expf(2.f * x) + 1.f);
}

struct HiLo { _Float16 hi, lo; };
__device__ __forceinline__ HiLo cvt_hilo(float v) {
    HiLo r;
    r.hi = (_Float16)v;
    r.lo = (_Float16)(v - (float)r.hi);
    return r;
}

__global__ __launch_bounds__(NT, 1) void plstm_scan_kernel(
    const float* __restrict__ x, const float* __restrict__ W,
    const float* __restrict__ U, const float* __restrict__ bias,
    const float* __restrict__ tau, const float* __restrict__ sph,
    const float* __restrict__ ln_g, const float* __restrict__ ln_b,
    const float* __restrict__ W1, const float* __restrict__ b1,
    const float* __restrict__ W2, const float* __restrict__ b2,
    float* __restrict__ out)
{
    __shared__ __align__(16) _Float16 Ah[NCELL * 8];   // 19.1 KB A (fp16 hi), fragment order
    __shared__ __align__(16) float zs[BT][ZP];         // 8.25 KB z tile
    __shared__ __align__(16) float bsz[128];
    __shared__ float red[16];
    __shared__ unsigned s_tag;

    const int tid = threadIdx.x;
    // Group by low bits: under round-robin dispatch all 16 blocks of a group
    // share blockIdx%8 -> likely same XCD (performance only, NOT correctness).
    const int bt = blockIdx.x & 15;    // batch group 0..15
    const int ut = blockIdx.x >> 4;    // unit block 0..15
    const int b0 = bt * BT;
    const int u0 = ut * UT;

    if (tid == 0) s_tag = (atomicAdd(&g_launch_cnt, 1u) >> 8) + 1u;

    // gate-update layout: all 512 threads -> (row 0..15, unit 0..31)
    const int urow = tid >> 5;
    const int uu   = tid & 31;

    const int wv = tid >> 6;           // wave = N-tile 0..7
    const int lane = tid & 63;
    const int n_ = lane & 15;
    const int q_ = lane >> 4;

    // ---- one-time: B fragments (this wave's 16 cols), fp16 hi/lo ----
    const int jg = (wv >> 1) * 512 + u0 + (wv & 1) * 16 + n_;
    h8 Bh[NFC], Bl[NFC];
    #pragma unroll
    for (int c = 0; c < NFC; ++c) {
        #pragma unroll
        for (int e = 0; e < 8; ++e) {
            const int kk = c * 32 + q_ * 8 + e;
            float v;
            if (c < 2) v = W[(size_t)kk * G4H + jg];
            else       v = U[(size_t)(kk - I_) * G4H + jg];
            const HiLo hl = cvt_hilo(v);
            Bh[c][e] = hl.hi;
            Bl[c][e] = hl.lo;
        }
    }
    if (tid < 128) bsz[tid] = bias[((tid >> 5) << 9) + u0 + (tid & 31)];

    __syncthreads();                       // publish s_tag (and bsz)
    const unsigned tagw = s_tag;
    const unsigned tagb = (tagw & 0xFFu) << 8;   // epoch tag byte, pre-shifted

    const float tau_r = tau[u0 + uu];
    const float s_r   = sph[u0 + uu];
    float c_st = 0.f;
    float h_st = 0.f;   // exact fp32 hprev: pure per-thread recurrence

    // staging geometry
    const int xr = (tid >> 4) & 15, xc4 = (tid & 15) << 2;  // x: tid<256, 1 float4
    const int cX = (tid & 15) >> 3, qX = ((tid & 15) >> 1) & 3;
    const int e0 = (tid & 1) << 2;
    const int fX = (cX * CSTR + qX * CPQ + xr) * 8 + e0;
    const int hr0 = tid >> 7, hk4 = (tid & 127) << 2;       // h: 4 rows x 4 packed cols
    const int cS = 2 + ((tid & 127) >> 3), qS = ((tid & 127) >> 1) & 3;

    float4 xv = *(const float4*)(x + ((size_t)(b0 + xr) * T_ + 0) * I_ + xc4);

    // MFMA A-frag read base (fragment order; same A broadcast to all 8 waves)
    const int fb = (q_ * CPQ + n_) * 8;

    int cur = 0;
    for (int t = 0; t < T_; ++t) {
        // ---- A) stage operands (tag-exact epoch poll; L2 fast path) ----
        if (t == 0) {
            const h8 z8 = {};
            for (int idx = tid; idx < NCELL; idx += NT)
                *(h8*)&Ah[idx * 8] = z8;
            __syncthreads();
            if (tid < 256) {
                h4v xh;
                xh[0] = (_Float16)xv.x; xh[1] = (_Float16)xv.y;
                xh[2] = (_Float16)xv.z; xh[3] = (_Float16)xv.w;
                *(h4v*)&Ah[fX] = xh;
            }
        } else {
            const unsigned* hb = g_hp[cur] + (size_t)(b0 + hr0) * H_ + hk4;
            const unsigned want = tagb | (unsigned)t;
            u4 a0, a1, a2, a3;
            bool ok;
            int tries = 0;
            bool dev = false;
            do {
                if (!dev) {
                    asm volatile(
                        "global_load_dwordx4 %0, %4, off sc0\n\t"
                        "global_load_dwordx4 %1, %5, off sc0\n\t"
                        "global_load_dwordx4 %2, %6, off sc0\n\t"
                        "global_load_dwordx4 %3, %7, off sc0\n\t"
                        "s_waitcnt vmcnt(0)"
                        : "=&v"(a0), "=&v"(a1), "=&v"(a2), "=&v"(a3)
                        : "v"(hb), "v"(hb + 4 * H_), "v"(hb + 8 * H_), "v"(hb + 12 * H_)
                        : "memory");
                    if (++tries >= POLL_N) dev = true;   // lockstep -> wave-uniform
                } else {
                    asm volatile(
                        "global_load_dwordx4 %0, %4, off sc0 sc1\n\t"
                        "global_load_dwordx4 %1, %5, off sc0 sc1\n\t"
                        "global_load_dwordx4 %2, %6, off sc0 sc1\n\t"
                        "global_load_dwordx4 %3, %7, off sc0 sc1\n\t"
                        "s_waitcnt vmcnt(0)"
                        : "=&v"(a0), "=&v"(a1), "=&v"(a2), "=&v"(a3)
                        : "v"(hb), "v"(hb + 4 * H_), "v"(hb + 8 * H_), "v"(hb + 12 * H_)
                        : "memory");
                }
                ok = ((a0[0] & 0xFFFFu) == want) & ((a0[1] & 0xFFFFu) == want)
                   & ((a0[2] & 0xFFFFu) == want) & ((a0[3] & 0xFFFFu) == want)
                   & ((a1[0] & 0xFFFFu) == want) & ((a1[1] & 0xFFFFu) == want)
                   & ((a1[2] & 0xFFFFu) == want) & ((a1[3] & 0xFFFFu) == want)
                   & ((a2[0] & 0xFFFFu) == want) & ((a2[1] & 0xFFFFu) == want)
                   & ((a2[2] & 0xFFFFu) == want) & ((a2[3] & 0xFFFFu) == want)
                   & ((a3[0] & 0xFFFFu) == want) & ((a3[1] & 0xFFFFu) == want)
                   & ((a3[2] & 0xFFFFu) == want) & ((a3[3] & 0xFFFFu) == want);
            } while (__ballot(!ok));
            const u4 av[4] = {a0, a1, a2, a3};
            #pragma unroll
            for (int it = 0; it < 4; ++it) {
                const int row = hr0 + 4 * it;
                const int fidx = (cS * CSTR + qS * CPQ + row) * 8 + e0;
                us4 uv;
                uv[0] = (unsigned short)(av[it][0] >> 16);
                uv[1] = (unsigned short)(av[it][1] >> 16);
                uv[2] = (unsigned short)(av[it][2] >> 16);
                uv[3] = (unsigned short)(av[it][3] >> 16);
                *(us4*)&Ah[fidx] = uv;   // fp16 payload, writer already converted
            }
        }
        __syncthreads();                                   // S1

        // prefetch next x
        if (tid < 256) {
            const int tn = (t < T_ - 1) ? t + 1 : t;
            xv = *(const float4*)(x + ((size_t)(b0 + xr) * T_ + tn) * I_ + xc4);
        }

        // ---- B) MFMA: A-hi x (B-hi + B-lo) ----
        f4 ac0 = {0.f, 0.f, 0.f, 0.f};
        f4 ac1 = {0.f, 0.f, 0.f, 0.f};
        #pragma unroll
        for (int c = 0; c < NFC; ++c) {
            const h8 ah = *(const h8*)&Ah[fb + c * (CSTR * 8)];
            ac0 = __builtin_amdgcn_mfma_f32_16x16x32_f16(ah, Bh[c], ac0, 0, 0, 0);
            ac1 = __builtin_amdgcn_mfma_f32_16x16x32_f16(ah, Bl[c], ac1, 0, 0, 0);
        }
        const f4 zt = ac0 + ac1;
        {
            const int colz = wv * 16 + n_;
            const int rz = q_ * 4;     // C-layout: row=(lane>>4)*4+reg (M=16)
            zs[rz + 0][colz] = zt[0];
            zs[rz + 1][colz] = zt[1];
            zs[rz + 2][colz] = zt[2];
            zs[rz + 3][colz] = zt[3];
        }
        __syncthreads();                                   // S2

        // ---- C) gates + phased time-gate; tagged paired h store (no drain) ----
        {
            const float zi = zs[urow][uu]       + bsz[uu];
            const float zf = zs[urow][32 + uu]  + bsz[32 + uu];
            const float zg = zs[urow][64 + uu]  + bsz[64 + uu];
            const float zo = zs[urow][96 + uu]  + bsz[96 + uu];
            const float si = fast_sigmoid(zi);
            const float sf = fast_sigmoid(zf);
            const float so = fast_sigmoid(zo);
            const float ct = sf * c_st + si * fast_tanh(zg);
            const float ht = so * fast_tanh(ct);
            float aa = (float)t - s_r;
            float rr = fmodf(aa, tau_r);
            if (rr < 0.f) rr += tau_r;
            const float phi = rr / tau_r;
            float kk;
            if (phi < 0.5f * R_ON_F)      kk = phi * (2.f / R_ON_F);
            else if (phi < R_ON_F)        kk = 2.f - phi * (2.f / R_ON_F);
            else                          kk = ALPHA_F * phi;
            const float hn = kk * ht + (1.f - kk) * h_st;
            c_st = kk * ct + (1.f - kk) * c_st;
            h_st = hn;
            if (t < T_ - 1) {
                const unsigned short hb16 = __builtin_bit_cast(unsigned short, (_Float16)hn);
                const unsigned packed = ((unsigned)hb16 << 16) | (tagb | (unsigned)(t + 1));
                unsigned* gp = g_hp[cur ^ 1] + (size_t)(b0 + urow) * H_ + (u0 + uu);
                // paired store: device-visible (IF$) + local-L2 fast path, same value
                asm volatile("global_store_dword %0, %1, off sc0 sc1\n\t"
                             "global_store_dword %0, %1, off sc0"
                             :: "v"(gp), "v"(packed) : "memory");
            } else {
                float* gp = g_hf + (size_t)(b0 + urow) * H_ + (u0 + uu);
                asm volatile("global_store_dword %0, %1, off sc0 sc1\n\ts_waitcnt vmcnt(0)"
                             :: "v"(gp), "v"(hn) : "memory");
            }
        }

        // ---- final-step handoff: drain + barrier + tagged flag publish ----
        if (t == T_ - 1) {
            __syncthreads();
            if (tid == 0) {
                unsigned fv = (tagw << 8) | 0xFFu;
                asm volatile("global_store_dword %0, %1, off sc0 sc1"
                             :: "v"(&g_flag[bt][ut].v), "v"(fv) : "memory");
            }
        }

        // ---- D) overlapped x staging ----
        if (t < T_ - 1 && tid < 256) {
            h4v xh;
            xh[0] = (_Float16)xv.x; xh[1] = (_Float16)xv.y;
            xh[2] = (_Float16)xv.z; xh[3] = (_Float16)xv.w;
            *(h4v*)&Ah[fX] = xh;
        }
        cur ^= 1;
    }

    // ---- epilogue: block (bt,ut) handles batch row b0+ut: LN + dense head ----
    {
        // wait for the whole group's final h stores (tagged flags, device scope)
        if (tid < 64) {
            const unsigned want = (tagw << 8) | 0xFFu;
            const unsigned* fp = &g_flag[bt][tid & 15].v;
            unsigned v;
            do {
                asm volatile("global_load_dword %0, %1, off sc0 sc1\n\ts_waitcnt vmcnt(0)"
                             : "=v"(v) : "v"(fp) : "memory");
            } while (__ballot(v != want));
        }
        __syncthreads();

        const int r = b0 + ut;         // bijective over [0,256)
        float hv;
        const float* hp = g_hf + (size_t)r * H_ + tid;
        asm volatile("global_load_dword %0, %1, off sc0 sc1\n\ts_waitcnt vmcnt(0)"
                     : "=v"(hv) : "v"(hp) : "memory");
        float s1 = hv, s2 = hv * hv;
        #pragma unroll
        for (int off = 32; off > 0; off >>= 1) {
            s1 += __shfl_down(s1, off, 64);
            s2 += __shfl_down(s2, off, 64);
        }
        const int ln = tid & 63;
        if (ln == 0) { red[wv] = s1; red[8 + wv] = s2; }
        __syncthreads();
        float S1 = 0.f, S2 = 0.f;
        #pragma unroll
        for (int w = 0; w < 8; ++w) { S1 += red[w]; S2 += red[8 + w]; }
        const float mu = S1 * (1.f / 512.f);
        const float var = S2 * (1.f / 512.f) - mu * mu;
        const float rstd = rsqrtf(var + LN_EPS_F);
        const float hn = (hv - mu) * rstd * ln_g[tid] + ln_b[tid];
        float w12 = 0.f;
        const float* w1p = W1 + (size_t)tid * 256;
        #pragma unroll 4
        for (int d = 0; d < 256; ++d) w12 = fmaf(w1p[d], W2[d], w12);
        float contrib = hn * w12;
        if (tid < 256) contrib = fmaf(b1[tid], W2[tid], contrib);
        #pragma unroll
        for (int off = 32; off > 0; off >>= 1) contrib += __shfl_down(contrib, off, 64);
        __syncthreads();
        if (ln == 0) red[wv] = contrib;
        __syncthreads();
        if (tid == 0) {
            float tot = b2[0];
            #pragma unroll
            for (int w = 0; w < 8; ++w) tot += red[w];
            out[r] = tot;
        }
    }
}

extern "C" void kernel_launch(void* const* d_in, const int* in_sizes, int n_in,
                              void* d_out, int out_size, void* d_ws, size_t ws_size,
                              hipStream_t stream) {
    const float* x   = (const float*)d_in[0];
    const float* W   = (const float*)d_in[1];
    const float* U   = (const float*)d_in[2];
    const float* b   = (const float*)d_in[3];
    const float* tau = (const float*)d_in[4];
    const float* s   = (const float*)d_in[5];
    const float* lng = (const float*)d_in[6];
    const float* lnb = (const float*)d_in[7];
    const float* W1  = (const float*)d_in[8];
    const float* b1  = (const float*)d_in[9];
    const float* W2  = (const float*)d_in[10];
    const float* b2  = (const float*)d_in[11];
    float* out = (float*)d_out;
    plstm_scan_kernel<<<dim3(NB), dim3(NT), 0, stream>>>(
        x, W, U, b, tau, s, lng, lnb, W1, b1, W2, b2, out);
}

// Round 6
// 1385.055 us; speedup vs baseline: 4.1790x; 4.1790x over previous
//
#include <hip/hip_runtime.h>
#include <cmath>

#define NB 256            // 16 batch groups x 16 unit blocks -> 1 block/CU
#define NT 512
#define NG 16             // batch groups
#define GB 16             // blocks per group
#define B_ 256
#define T_ 256
#define I_ 64
#define H_ 512
#define G4H 2048
#define BT 16             // batch rows per block
#define UT 32             // hidden units per block -> 128 z cols, 8 waves
#define NFC 18            // K chunks of 32
#define CPQ 17            // cells (16B) per q-group: 16 rows + 1 pad
#define CSTR 68           // cell stride per chunk (4*17)
#define NCELL 1224        // 18*68
#define R_ON_F 0.05f
#define ALPHA_F 1.0e-3f
#define LN_EPS_F 1.0e-5f

typedef _Float16 h8 __attribute__((ext_vector_type(8)));
typedef _Float16 h4v __attribute__((ext_vector_type(4)));
typedef float f4 __attribute__((ext_vector_type(4)));
typedef float v4f __attribute__((ext_vector_type(4)));
typedef unsigned u4 __attribute__((ext_vector_type(4)));
typedef unsigned short us4 __attribute__((ext_vector_type(4)));

// Packed hidden-state double buffer: fp16(h)<<16 | (launch_tag<<8 | t+1).
// DEVICE SCOPE ONLY (sc0 sc1) -- R4/R5 proved XCD co-location cannot be
// assumed and L2-scope polling reads stale clean lines forever.
// Launch-tagged epochs: stale lines never equality-match (every slot is
// rewritten every launch, so stale tag == tag_cur - 1), so no zeroing and
// no startup barrier are needed.
__device__ __align__(16) unsigned g_hp[2][B_ * H_];
// Exact fp32 final h for the LN/dense epilogue (written only at t = T_-1).
__device__ __align__(16) float g_hf[B_ * H_];

struct alignas(256) PadCnt { unsigned v; unsigned pad[63]; };
__device__ PadCnt g_flag[NG][GB];   // FINAL handoff only; tagged values
__device__ unsigned g_launch_cnt;   // never reset; tag = (cnt/NB)+1

__device__ __forceinline__ float fast_sigmoid(float x) {
    return __builtin_amdgcn_rcpf(1.f + __expf(-x));
}
__device__ __forceinline__ float fast_tanh(float x) {
    return 1.f - 2.f * __builtin_amdgcn_rcpf(__expf(2.f * x) + 1.f);
}

struct HiLo { _Float16 hi, lo; };
__device__ __forceinline__ HiLo cvt_hilo(float v) {
    HiLo r;
    r.hi = (_Float16)v;
    r.lo = (_Float16)(v - (float)r.hi);
    return r;
}

__global__ __launch_bounds__(NT, 1) void plstm_scan_kernel(
    const float* __restrict__ x, const float* __restrict__ W,
    const float* __restrict__ U, const float* __restrict__ bias,
    const float* __restrict__ tau, const float* __restrict__ sph,
    const float* __restrict__ ln_g, const float* __restrict__ ln_b,
    const float* __restrict__ W1, const float* __restrict__ b1,
    const float* __restrict__ W2, const float* __restrict__ b2,
    float* __restrict__ out)
{
    // Double-buffered A tile (fp16, fragment order): one barrier per step.
    __shared__ __align__(16) _Float16 Ah[2][NCELL * 8];   // 38.25 KB
    __shared__ __align__(16) float kt[T_ * UT];           // 32 KB time-gate table
    __shared__ float red[16];
    __shared__ unsigned s_tag;

    const int tid = threadIdx.x;
    const int bt = blockIdx.x & 15;    // batch group 0..15
    const int ut = blockIdx.x >> 4;    // unit block 0..15
    const int b0 = bt * BT;
    const int u0 = ut * UT;

    if (tid == 0) s_tag = (atomicAdd(&g_launch_cnt, 1u) >> 8) + 1u;

    const int wv = tid >> 6;           // wave 0..7
    const int lane = tid & 63;
    const int n_ = lane & 15;
    const int q_ = lane >> 4;

    // ---- B fragments: wave wv owns all 4 gates of units u0+wv*4 .. +3.
    //      lane col n_: gate = n_&3, unit_j = n_>>2
    //      global z-col jg = gate*512 + u0 + wv*4 + unit_j  (z = [i f g o])
    const int jg = (n_ & 3) * H_ + u0 + wv * 4 + (n_ >> 2);
    h8 Bh[NFC], Bl[NFC];
    #pragma unroll
    for (int c = 0; c < NFC; ++c) {
        #pragma unroll
        for (int e = 0; e < 8; ++e) {
            const int kk = c * 32 + q_ * 8 + e;
            float v;
            if (c < 2) v = W[(size_t)kk * G4H + jg];
            else       v = U[(size_t)(kk - I_) * G4H + jg];
            const HiLo hl = cvt_hilo(v);
            Bh[c][e] = hl.hi;
            Bl[c][e] = hl.lo;
        }
    }
    const float bv = bias[jg];         // bias folded into MFMA C-input

    // ---- time-gate table k[t][unit_local] (data-independent) ----
    for (int idx = tid; idx < T_ * UT; idx += NT) {
        const int tt = idx >> 5, ul = idx & 31;
        const float ta = tau[u0 + ul];
        float aa = (float)tt - sph[u0 + ul];
        float rr = fmodf(aa, ta);
        if (rr < 0.f) rr += ta;
        const float phi = rr / ta;
        float kk;
        if (phi < 0.5f * R_ON_F)      kk = phi * (2.f / R_ON_F);
        else if (phi < R_ON_F)        kk = 2.f - phi * (2.f / R_ON_F);
        else                          kk = ALPHA_F * phi;
        kt[idx] = kk;
    }
    __syncthreads();                   // publish s_tag + kt
    const unsigned tagw = s_tag;
    const unsigned tagb = (tagw & 0xFFu) << 8;

    // ---- per-lane gate-cell ownership: (row, unit_local) ----
    const int crow = (q_ << 2) + ((lane >> 2) & 3);   // 0..15
    const int cul  = (wv << 2) + (lane & 3);          // 0..31
    float c_st = 0.f;
    float h_st = 0.f;

    // staging geometry (unchanged from verified R3)
    const int xr = (tid >> 4) & 15, xc4 = (tid & 15) << 2;  // x: tid<256, 1 float4
    const int cX = (tid & 15) >> 3, qX = ((tid & 15) >> 1) & 3;
    const int e0 = (tid & 1) << 2;
    const int fX = (cX * CSTR + qX * CPQ + xr) * 8 + e0;
    const int hr0 = tid >> 7, hk4 = (tid & 127) << 2;       // h: 4 rows x 4 packed cols
    const int cS = 2 + ((tid & 127) >> 3), qS = ((tid & 127) >> 1) & 3;

    float4 xv = *(const float4*)(x + ((size_t)(b0 + xr) * T_ + 0) * I_ + xc4);

    const int fb = (q_ * CPQ + n_) * 8;   // A-frag read base (fragment order)

    int cur = 0;
    for (int t = 0; t < T_; ++t) {
        // ---- A) stage h(t) into Ah[t&1] (epoch poll, device scope) ----
        if (t == 0) {
            _Float16* A0 = &Ah[0][0];
            const h8 z8 = {};
            for (int idx = tid; idx < 2 * NCELL; idx += NT)
                *(h8*)&A0[idx * 8] = z8;
            __syncthreads();
            if (tid < 256) {
                h4v xh;
                xh[0] = (_Float16)xv.x; xh[1] = (_Float16)xv.y;
                xh[2] = (_Float16)xv.z; xh[3] = (_Float16)xv.w;
                *(h4v*)&Ah[0][fX] = xh;
            }
        } else {
            const unsigned* hb = g_hp[cur] + (size_t)(b0 + hr0) * H_ + hk4;
            const unsigned want = tagb | (unsigned)t;
            u4 a0, a1, a2, a3;
            bool ok;
            do {
                asm volatile(
                    "global_load_dwordx4 %0, %4, off sc0 sc1\n\t"
                    "global_load_dwordx4 %1, %5, off sc0 sc1\n\t"
                    "global_load_dwordx4 %2, %6, off sc0 sc1\n\t"
                    "global_load_dwordx4 %3, %7, off sc0 sc1\n\t"
                    "s_waitcnt vmcnt(0)"
                    : "=&v"(a0), "=&v"(a1), "=&v"(a2), "=&v"(a3)
                    : "v"(hb), "v"(hb + 4 * H_), "v"(hb + 8 * H_), "v"(hb + 12 * H_)
                    : "memory");
                ok = ((a0[0] & 0xFFFFu) == want) & ((a0[1] & 0xFFFFu) == want)
                   & ((a0[2] & 0xFFFFu) == want) & ((a0[3] & 0xFFFFu) == want)
                   & ((a1[0] & 0xFFFFu) == want) & ((a1[1] & 0xFFFFu) == want)
                   & ((a1[2] & 0xFFFFu) == want) & ((a1[3] & 0xFFFFu) == want)
                   & ((a2[0] & 0xFFFFu) == want) & ((a2[1] & 0xFFFFu) == want)
                   & ((a2[2] & 0xFFFFu) == want) & ((a2[3] & 0xFFFFu) == want)
                   & ((a3[0] & 0xFFFFu) == want) & ((a3[1] & 0xFFFFu) == want)
                   & ((a3[2] & 0xFFFFu) == want) & ((a3[3] & 0xFFFFu) == want);
            } while (__ballot(!ok));
            const u4 av[4] = {a0, a1, a2, a3};
            _Float16* Ab = &Ah[t & 1][0];
            #pragma unroll
            for (int it = 0; it < 4; ++it) {
                const int row = hr0 + 4 * it;
                const int fidx = (cS * CSTR + qS * CPQ + row) * 8 + e0;
                us4 uv;
                uv[0] = (unsigned short)(av[it][0] >> 16);
                uv[1] = (unsigned short)(av[it][1] >> 16);
                uv[2] = (unsigned short)(av[it][2] >> 16);
                uv[3] = (unsigned short)(av[it][3] >> 16);
                *(us4*)&Ab[fidx] = uv;
            }
        }
        __syncthreads();                                   // S1 (only barrier)

        // prefetch next x
        if (tid < 256) {
            const int tn = (t < T_ - 1) ? t + 1 : t;
            xv = *(const float4*)(x + ((size_t)(b0 + xr) * T_ + tn) * I_ + xc4);
        }

        // ---- B) MFMA: A-hi x (B-hi + B-lo), bias as C-in ----
        f4 ac0 = {bv, bv, bv, bv};
        f4 ac1 = {0.f, 0.f, 0.f, 0.f};
        {
            const _Float16* Ab = &Ah[t & 1][0];
            #pragma unroll
            for (int c = 0; c < NFC; ++c) {
                const h8 ah = *(const h8*)&Ab[fb + c * (CSTR * 8)];
                ac0 = __builtin_amdgcn_mfma_f32_16x16x32_f16(ah, Bh[c], ac0, 0, 0, 0);
                ac1 = __builtin_amdgcn_mfma_f32_16x16x32_f16(ah, Bl[c], ac1, 0, 0, 0);
            }
        }
        const f4 zt = ac0 + ac1;       // z[row=q_*4+r][col=n_] per lane

        // ---- C) in-wave gate gather (replaces zs LDS + S2 barrier) ----
        // target lane (q_, n_) owns cell (crow, cul); gate g comes from
        // source lane q_*16 + 4*(n_&3) + g, register r = n_>>2.
        {
            const int sb = (lane & 48) + ((lane & 3) << 2);
            float tz0[4], tz1[4], tz2[4], tz3[4];
            #pragma unroll
            for (int g = 0; g < 4; ++g) {
                tz0[g] = __shfl(zt[0], sb + g, 64);
                tz1[g] = __shfl(zt[1], sb + g, 64);
                tz2[g] = __shfl(zt[2], sb + g, 64);
                tz3[g] = __shfl(zt[3], sb + g, 64);
            }
            const int rs = (lane >> 2) & 3;
            float z4[4];
            #pragma unroll
            for (int g = 0; g < 4; ++g)
                z4[g] = (rs == 0) ? tz0[g] : (rs == 1) ? tz1[g]
                      : (rs == 2) ? tz2[g] : tz3[g];

            const float si = fast_sigmoid(z4[0]);
            const float sf = fast_sigmoid(z4[1]);
            const float so = fast_sigmoid(z4[3]);
            const float ct = sf * c_st + si * fast_tanh(z4[2]);
            const float ht = so * fast_tanh(ct);
            const float kk = kt[(t << 5) + cul];
            const float hn = kk * ht + (1.f - kk) * h_st;
            c_st = kk * ct + (1.f - kk) * c_st;
            h_st = hn;
            if (t < T_ - 1) {
                const unsigned short hb16 = __builtin_bit_cast(unsigned short, (_Float16)hn);
                const unsigned packed = ((unsigned)hb16 << 16) | (tagb | (unsigned)(t + 1));
                unsigned* gp = g_hp[cur ^ 1] + (size_t)(b0 + crow) * H_ + (u0 + cul);
                asm volatile("global_store_dword %0, %1, off sc0 sc1"
                             :: "v"(gp), "v"(packed) : "memory");
            } else {
                float* gp = g_hf + (size_t)(b0 + crow) * H_ + (u0 + cul);
                asm volatile("global_store_dword %0, %1, off sc0 sc1\n\ts_waitcnt vmcnt(0)"
                             :: "v"(gp), "v"(hn) : "memory");
            }
        }

        // ---- final-step handoff: drain + barrier + tagged flag publish ----
        if (t == T_ - 1) {
            __syncthreads();
            if (tid == 0) {
                unsigned fv = (tagw << 8) | 0xFFu;
                asm volatile("global_store_dword %0, %1, off sc0 sc1"
                             :: "v"(&g_flag[bt][ut].v), "v"(fv) : "memory");
            }
        }

        // ---- D) stage x(t+1) into the other buffer ----
        if (t < T_ - 1 && tid < 256) {
            h4v xh;
            xh[0] = (_Float16)xv.x; xh[1] = (_Float16)xv.y;
            xh[2] = (_Float16)xv.z; xh[3] = (_Float16)xv.w;
            *(h4v*)&Ah[(t + 1) & 1][fX] = xh;
        }
        cur ^= 1;
    }

    // ---- epilogue: block (bt,ut) handles batch row b0+ut: LN + dense head ----
    {
        if (tid < 64) {
            const unsigned want = (tagw << 8) | 0xFFu;
            const unsigned* fp = &g_flag[bt][tid & 15].v;
            unsigned v;
            do {
                asm volatile("global_load_dword %0, %1, off sc0 sc1\n\ts_waitcnt vmcnt(0)"
                             : "=v"(v) : "v"(fp) : "memory");
            } while (__ballot(v != want));
        }
        __syncthreads();

        const int r = b0 + ut;         // bijective over [0,256)
        float hv;
        const float* hp = g_hf + (size_t)r * H_ + tid;
        asm volatile("global_load_dword %0, %1, off sc0 sc1\n\ts_waitcnt vmcnt(0)"
                     : "=v"(hv) : "v"(hp) : "memory");
        float s1 = hv, s2 = hv * hv;
        #pragma unroll
        for (int off = 32; off > 0; off >>= 1) {
            s1 += __shfl_down(s1, off, 64);
            s2 += __shfl_down(s2, off, 64);
        }
        const int ln = tid & 63;
        if (ln == 0) { red[wv] = s1; red[8 + wv] = s2; }
        __syncthreads();
        float S1 = 0.f, S2 = 0.f;
        #pragma unroll
        for (int w = 0; w < 8; ++w) { S1 += red[w]; S2 += red[8 + w]; }
        const float mu = S1 * (1.f / 512.f);
        const float var = S2 * (1.f / 512.f) - mu * mu;
        const float rstd = rsqrtf(var + LN_EPS_F);
        const float hn = (hv - mu) * rstd * ln_g[tid] + ln_b[tid];
        float w12 = 0.f;
        const float* w1p = W1 + (size_t)tid * 256;
        #pragma unroll 4
        for (int d = 0; d < 256; ++d) w12 = fmaf(w1p[d], W2[d], w12);
        float contrib = hn * w12;
        if (tid < 256) contrib = fmaf(b1[tid], W2[tid], contrib);
        #pragma unroll
        for (int off = 32; off > 0; off >>= 1) contrib += __shfl_down(contrib, off, 64);
        __syncthreads();
        if (ln == 0) red[wv] = contrib;
        __syncthreads();
        if (tid == 0) {
            float tot = b2[0];
            #pragma unroll
            for (int w = 0; w < 8; ++w) tot += red[w];
            out[r] = tot;
        }
    }
}

extern "C" void kernel_launch(void* const* d_in, const int* in_sizes, int n_in,
                              void* d_out, int out_size, void* d_ws, size_t ws_size,
                              hipStream_t stream) {
    const float* x   = (const float*)d_in[0];
    const float* W   = (const float*)d_in[1];
    const float* U   = (const float*)d_in[2];
    const float* b   = (const float*)d_in[3];
    const float* tau = (const float*)d_in[4];
    const float* s   = (const float*)d_in[5];
    const float* lng = (const float*)d_in[6];
    const float* lnb = (const float*)d_in[7];
    const float* W1  = (const float*)d_in[8];
    const float* b1  = (const float*)d_in[9];
    const float* W2  = (const float*)d_in[10];
    const float* b2  = (const float*)d_in[11];
    float* out = (float*)d_out;
    plstm_scan_kernel<<<dim3(NB), dim3(NT), 0, stream>>>(
        x, W, U, b, tau, s, lng, lnb, W1, b1, W2, b2, out);
}

// Round 7
// 763.018 us; speedup vs baseline: 7.5858x; 1.8152x over previous
//
#include <hip/hip_runtime.h>
#include <cmath>

#define NB 256            // 16 batch groups x 16 unit blocks -> 1 block/CU
#define NT 512
#define NG 16             // batch groups
#define GB 16             // blocks per group
#define B_ 256
#define T_ 256
#define I_ 64
#define H_ 512
#define G4H 2048
#define BT 16             // batch rows per block
#define UT 32             // hidden units per block -> 128 z cols, 8 waves
#define ZP 132            // zs row stride (128 + 4)
#define NFC 18            // K chunks of 32
#define CPQ 17            // cells (16B) per q-group: 16 rows + 1 pad
#define CSTR 68           // cell stride per chunk (4*17)
#define NCELL 1224        // 18*68
#define R_ON_F 0.05f
#define ALPHA_F 1.0e-3f
#define LN_EPS_F 1.0e-5f

typedef _Float16 h8 __attribute__((ext_vector_type(8)));
typedef _Float16 h4v __attribute__((ext_vector_type(4)));
typedef float f4 __attribute__((ext_vector_type(4)));
typedef float v4f __attribute__((ext_vector_type(4)));
typedef unsigned u4 __attribute__((ext_vector_type(4)));
typedef unsigned short us4 __attribute__((ext_vector_type(4)));

// Packed hidden-state double buffer: fp16(h)<<16 | (launch_tag<<8 | t+1).
// DEVICE SCOPE ONLY (sc0 sc1): R4/R5 proved XCD co-location can't be assumed
// and L2-scope polling reads stale clean lines forever.
// Launch-tagged epochs: stale data never equality-matches, so no zeroing and
// no startup barrier are needed (verified R5/R6).
// STORE LAYOUT IS SACRED (R6 lesson): gate thread (urow,uu) => each wave
// stores 2 rows x 128B contiguous; scattering this doubled WRITE_SIZE and
// cost 2x end-to-end.
__device__ __align__(16) unsigned g_hp[2][B_ * H_];
// Exact fp32 final h for the LN/dense epilogue (written only at t = T_-1).
__device__ __align__(16) float g_hf[B_ * H_];

struct alignas(256) PadCnt { unsigned v; unsigned pad[63]; };
__device__ PadCnt g_flag[NG][GB];   // FINAL handoff only; tagged values
__device__ unsigned g_launch_cnt;   // never reset; +NB per launch => tag = cnt>>8

__device__ __forceinline__ float fast_sigmoid(float x) {
    return __builtin_amdgcn_rcpf(1.f + __expf(-x));
}
__device__ __forceinline__ float fast_tanh(float x) {
    return 1.f - 2.f * __builtin_amdgcn_rcpf(__expf(2.f * x) + 1.f);
}

struct HiLo { _Float16 hi, lo; };
__device__ __forceinline__ HiLo cvt_hilo(float v) {
    HiLo r;
    r.hi = (_Float16)v;
    r.lo = (_Float16)(v - (float)r.hi);
    return r;
}

__global__ __launch_bounds__(NT, 1) void plstm_scan_kernel(
    const float* __restrict__ x, const float* __restrict__ W,
    const float* __restrict__ U, const float* __restrict__ bias,
    const float* __restrict__ tau, const float* __restrict__ sph,
    const float* __restrict__ ln_g, const float* __restrict__ ln_b,
    const float* __restrict__ W1, const float* __restrict__ b1,
    const float* __restrict__ W2, const float* __restrict__ b2,
    float* __restrict__ out)
{
    __shared__ __align__(16) _Float16 Ah[NCELL * 8];   // 19.1 KB A (fp16 hi), fragment order
    __shared__ __align__(16) float zs[BT][ZP];         // 8.25 KB z tile
    __shared__ __align__(16) float kt[T_ * UT];        // 32 KB time-gate table
    __shared__ float red[16];
    __shared__ unsigned s_tag;

    const int tid = threadIdx.x;
    const int bt = blockIdx.x >> 4;    // batch group 0..15
    const int ut = blockIdx.x & 15;    // unit block 0..15
    const int b0 = bt * BT;
    const int u0 = ut * UT;

    if (tid == 0) s_tag = (atomicAdd(&g_launch_cnt, 1u) >> 8) + 1u;

    const int wv = tid >> 6;           // wave = N-tile 0..7
    const int lane = tid & 63;
    const int n_ = lane & 15;
    const int q_ = lane >> 4;

    // ---- one-time: B fragments (this wave's 16 cols), fp16 hi/lo ----
    const int jg = (wv >> 1) * 512 + u0 + (wv & 1) * 16 + n_;
    h8 Bh[NFC], Bl[NFC];
    #pragma unroll
    for (int c = 0; c < NFC; ++c) {
        #pragma unroll
        for (int e = 0; e < 8; ++e) {
            const int kk = c * 32 + q_ * 8 + e;
            float v;
            if (c < 2) v = W[(size_t)kk * G4H + jg];
            else       v = U[(size_t)(kk - I_) * G4H + jg];
            const HiLo hl = cvt_hilo(v);
            Bh[c][e] = hl.hi;
            Bl[c][e] = hl.lo;
        }
    }
    const float bv = bias[jg];         // bias folded into MFMA C-input

    // ---- one-time: time-gate table k[t][unit_local] (data-independent) ----
    for (int idx = tid; idx < T_ * UT; idx += NT) {
        const int tt = idx >> 5, ul = idx & 31;
        const float ta = tau[u0 + ul];
        float aa = (float)tt - sph[u0 + ul];
        float rr = fmodf(aa, ta);
        if (rr < 0.f) rr += ta;
        const float phi = rr / ta;
        float kk;
        if (phi < 0.5f * R_ON_F)      kk = phi * (2.f / R_ON_F);
        else if (phi < R_ON_F)        kk = 2.f - phi * (2.f / R_ON_F);
        else                          kk = ALPHA_F * phi;
        kt[idx] = kk;
    }
    __syncthreads();                   // publish s_tag + kt
    const unsigned tagw = s_tag;
    const unsigned tagb = (tagw & 0xFFu) << 8;

    // gate-update layout: all 512 threads -> (row 0..15, unit 0..31)
    const int urow = tid >> 5;
    const int uu   = tid & 31;
    float c_st = 0.f;
    float h_st = 0.f;   // exact fp32 hprev: pure per-thread recurrence

    // staging geometry
    const int xr = (tid >> 4) & 15, xc4 = (tid & 15) << 2;  // x: tid<256, 1 float4
    const int cX = (tid & 15) >> 3, qX = ((tid & 15) >> 1) & 3;
    const int e0 = (tid & 1) << 2;
    const int fX = (cX * CSTR + qX * CPQ + xr) * 8 + e0;
    const int hr0 = tid >> 7, hk4 = (tid & 127) << 2;       // h: 4 rows x 4 packed cols
    const int cS = 2 + ((tid & 127) >> 3), qS = ((tid & 127) >> 1) & 3;

    float4 xv = *(const float4*)(x + ((size_t)(b0 + xr) * T_ + 0) * I_ + xc4);

    // MFMA A-frag read base (fragment order; same A broadcast to all 8 waves)
    const int fb = (q_ * CPQ + n_) * 8;

    int cur = 0;
    for (int t = 0; t < T_; ++t) {
        // ---- A) stage operands (tag-exact epoch poll, device scope) ----
        if (t == 0) {
            const h8 z8 = {};
            for (int idx = tid; idx < NCELL; idx += NT)
                *(h8*)&Ah[idx * 8] = z8;
            __syncthreads();
            if (tid < 256) {
                h4v xh;
                xh[0] = (_Float16)xv.x; xh[1] = (_Float16)xv.y;
                xh[2] = (_Float16)xv.z; xh[3] = (_Float16)xv.w;
                *(h4v*)&Ah[fX] = xh;
            }
        } else {
            const unsigned* hb = g_hp[cur] + (size_t)(b0 + hr0) * H_ + hk4;
            const unsigned want = tagb | (unsigned)t;
            u4 a0, a1, a2, a3;
            bool ok;
            do {
                asm volatile(
                    "global_load_dwordx4 %0, %4, off sc0 sc1\n\t"
                    "global_load_dwordx4 %1, %5, off sc0 sc1\n\t"
                    "global_load_dwordx4 %2, %6, off sc0 sc1\n\t"
                    "global_load_dwordx4 %3, %7, off sc0 sc1\n\t"
                    "s_waitcnt vmcnt(0)"
                    : "=&v"(a0), "=&v"(a1), "=&v"(a2), "=&v"(a3)
                    : "v"(hb), "v"(hb + 4 * H_), "v"(hb + 8 * H_), "v"(hb + 12 * H_)
                    : "memory");
                ok = ((a0[0] & 0xFFFFu) == want) & ((a0[1] & 0xFFFFu) == want)
                   & ((a0[2] & 0xFFFFu) == want) & ((a0[3] & 0xFFFFu) == want)
                   & ((a1[0] & 0xFFFFu) == want) & ((a1[1] & 0xFFFFu) == want)
                   & ((a1[2] & 0xFFFFu) == want) & ((a1[3] & 0xFFFFu) == want)
                   & ((a2[0] & 0xFFFFu) == want) & ((a2[1] & 0xFFFFu) == want)
                   & ((a2[2] & 0xFFFFu) == want) & ((a2[3] & 0xFFFFu) == want)
                   & ((a3[0] & 0xFFFFu) == want) & ((a3[1] & 0xFFFFu) == want)
                   & ((a3[2] & 0xFFFFu) == want) & ((a3[3] & 0xFFFFu) == want);
            } while (__ballot(!ok));
            const u4 av[4] = {a0, a1, a2, a3};
            #pragma unroll
            for (int it = 0; it < 4; ++it) {
                const int row = hr0 + 4 * it;
                const int fidx = (cS * CSTR + qS * CPQ + row) * 8 + e0;
                us4 uv;
                uv[0] = (unsigned short)(av[it][0] >> 16);
                uv[1] = (unsigned short)(av[it][1] >> 16);
                uv[2] = (unsigned short)(av[it][2] >> 16);
                uv[3] = (unsigned short)(av[it][3] >> 16);
                *(us4*)&Ah[fidx] = uv;   // fp16 payload, writer already converted
            }
        }
        __syncthreads();                                   // S1

        // prefetch next x
        if (tid < 256) {
            const int tn = (t < T_ - 1) ? t + 1 : t;
            xv = *(const float4*)(x + ((size_t)(b0 + xr) * T_ + tn) * I_ + xc4);
        }

        // ---- B) MFMA: A-hi x (B-hi + B-lo), bias as C-in ----
        f4 ac0 = {bv, bv, bv, bv};
        f4 ac1 = {0.f, 0.f, 0.f, 0.f};
        #pragma unroll
        for (int c = 0; c < NFC; ++c) {
            const h8 ah = *(const h8*)&Ah[fb + c * (CSTR * 8)];
            ac0 = __builtin_amdgcn_mfma_f32_16x16x32_f16(ah, Bh[c], ac0, 0, 0, 0);
            ac1 = __builtin_amdgcn_mfma_f32_16x16x32_f16(ah, Bl[c], ac1, 0, 0, 0);
        }
        const f4 zt = ac0 + ac1;
        {
            const int colz = wv * 16 + n_;
            const int rz = q_ * 4;     // C-layout: row=(lane>>4)*4+reg (M=16)
            zs[rz + 0][colz] = zt[0];
            zs[rz + 1][colz] = zt[1];
            zs[rz + 2][colz] = zt[2];
            zs[rz + 3][colz] = zt[3];
        }
        __syncthreads();                                   // S2

        // ---- C) gates + table time-gate; tagged h store (coalesced layout) ----
        {
            const float zi = zs[urow][uu];
            const float zf = zs[urow][32 + uu];
            const float zg = zs[urow][64 + uu];
            const float zo = zs[urow][96 + uu];
            const float si = fast_sigmoid(zi);
            const float sf = fast_sigmoid(zf);
            const float so = fast_sigmoid(zo);
            const float ct = sf * c_st + si * fast_tanh(zg);
            const float ht = so * fast_tanh(ct);
            const float kk = kt[(t << 5) + uu];
            const float hn = kk * ht + (1.f - kk) * h_st;
            c_st = kk * ct + (1.f - kk) * c_st;
            h_st = hn;
            if (t < T_ - 1) {
                const unsigned short hb16 = __builtin_bit_cast(unsigned short, (_Float16)hn);
                const unsigned packed = ((unsigned)hb16 << 16) | (tagb | (unsigned)(t + 1));
                unsigned* gp = g_hp[cur ^ 1] + (size_t)(b0 + urow) * H_ + (u0 + uu);
                asm volatile("global_store_dword %0, %1, off sc0 sc1"
                             :: "v"(gp), "v"(packed) : "memory");
            } else {
                float* gp = g_hf + (size_t)(b0 + urow) * H_ + (u0 + uu);
                asm volatile("global_store_dword %0, %1, off sc0 sc1\n\ts_waitcnt vmcnt(0)"
                             :: "v"(gp), "v"(hn) : "memory");
            }
        }

        // ---- final-step handoff: drain + barrier + tagged flag publish ----
        if (t == T_ - 1) {
            __syncthreads();
            if (tid == 0) {
                unsigned fv = (tagw << 8) | 0xFFu;
                asm volatile("global_store_dword %0, %1, off sc0 sc1"
                             :: "v"(&g_flag[bt][ut].v), "v"(fv) : "memory");
            }
        }

        // ---- D) overlapped x staging ----
        if (t < T_ - 1 && tid < 256) {
            h4v xh;
            xh[0] = (_Float16)xv.x; xh[1] = (_Float16)xv.y;
            xh[2] = (_Float16)xv.z; xh[3] = (_Float16)xv.w;
            *(h4v*)&Ah[fX] = xh;
        }
        cur ^= 1;
    }

    // ---- epilogue: block (bt,ut) handles batch row b0+ut: LN + dense head ----
    {
        if (tid < 64) {
            const unsigned want = (tagw << 8) | 0xFFu;
            const unsigned* fp = &g_flag[bt][tid & 15].v;
            unsigned v;
            do {
                asm volatile("global_load_dword %0, %1, off sc0 sc1\n\ts_waitcnt vmcnt(0)"
                             : "=v"(v) : "v"(fp) : "memory");
            } while (__ballot(v != want));
        }
        __syncthreads();

        const int r = b0 + ut;         // bijective over [0,256)
        float hv;
        const float* hp = g_hf + (size_t)r * H_ + tid;
        asm volatile("global_load_dword %0, %1, off sc0 sc1\n\ts_waitcnt vmcnt(0)"
                     : "=v"(hv) : "v"(hp) : "memory");
        float s1 = hv, s2 = hv * hv;
        #pragma unroll
        for (int off = 32; off > 0; off >>= 1) {
            s1 += __shfl_down(s1, off, 64);
            s2 += __shfl_down(s2, off, 64);
        }
        const int ln = tid & 63;
        if (ln == 0) { red[wv] = s1; red[8 + wv] = s2; }
        __syncthreads();
        float S1 = 0.f, S2 = 0.f;
        #pragma unroll
        for (int w = 0; w < 8; ++w) { S1 += red[w]; S2 += red[8 + w]; }
        const float mu = S1 * (1.f / 512.f);
        const float var = S2 * (1.f / 512.f) - mu * mu;
        const float rstd = rsqrtf(var + LN_EPS_F);
        const float hn = (hv - mu) * rstd * ln_g[tid] + ln_b[tid];
        float w12 = 0.f;
        const float* w1p = W1 + (size_t)tid * 256;
        #pragma unroll 4
        for (int d = 0; d < 256; ++d) w12 = fmaf(w1p[d], W2[d], w12);
        float contrib = hn * w12;
        if (tid < 256) contrib = fmaf(b1[tid], W2[tid], contrib);
        #pragma unroll
        for (int off = 32; off > 0; off >>= 1) contrib += __shfl_down(contrib, off, 64);
        __syncthreads();
        if (ln == 0) red[wv] = contrib;
        __syncthreads();
        if (tid == 0) {
            float tot = b2[0];
            #pragma unroll
            for (int w = 0; w < 8; ++w) tot += red[w];
            out[r] = tot;
        }
    }
}

extern "C" void kernel_launch(void* const* d_in, const int* in_sizes, int n_in,
                              void* d_out, int out_size, void* d_ws, size_t ws_size,
                              hipStream_t stream) {
    const float* x   = (const float*)d_in[0];
    const float* W   = (const float*)d_in[1];
    const float* U   = (const float*)d_in[2];
    const float* b   = (const float*)d_in[3];
    const float* tau = (const float*)d_in[4];
    const float* s   = (const float*)d_in[5];
    const float* lng = (const float*)d_in[6];
    const float* lnb = (const float*)d_in[7];
    const float* W1  = (const float*)d_in[8];
    const float* b1  = (const float*)d_in[9];
    const float* W2  = (const float*)d_in[10];
    const float* b2  = (const float*)d_in[11];
    float* out = (float*)d_out;
    plstm_scan_kernel<<<dim3(NB), dim3(NT), 0, stream>>>(
        x, W, U, b, tau, s, lng, lnb, W1, b1, W2, b2, out);
}